// Round 2
// baseline (1233.234 us; speedup 1.0000x reference)
//
#include <hip/hip_runtime.h>

// ---------------------------------------------------------------------------
// GQA forward: out = softmax_causal((xWq)(xWk)^T/sqrt(128)) (xWv) Wo + biases
// B=2, T=2048, D=4096, H=32, G=8, HD=128, REP=4
// Strategy: cast everything to bf16 (threshold 9.25e-2 allows it), run all
// matmuls on MFMA 16x16x32 bf16. Weights are cast+transposed so every GEMM
// is B^T-layout (K-contiguous for both operands -> ds_read_b128 fragments).
// ---------------------------------------------------------------------------

typedef unsigned short u16;
using s16x8 = __attribute__((ext_vector_type(8))) short;   // 8 x bf16 (4 VGPR)
using f32x4 = __attribute__((ext_vector_type(4))) float;   // MFMA C/D
using u16x4 = __attribute__((ext_vector_type(4))) u16;

#define Bc   2
#define Tc   2048
#define Dc   4096
#define GHDc 1024   // G*HD
#define Hc   32

__device__ __forceinline__ u16 f2bf(float x) {
  unsigned b = __float_as_uint(x);
  return (u16)((b + 0x7FFFu + ((b >> 16) & 1u)) >> 16);   // RTNE
}

__device__ __forceinline__ void gld_lds16(const void* g, void* l) {
  auto gp = reinterpret_cast<const __attribute__((address_space(1))) char*>(
      reinterpret_cast<uintptr_t>(g));
  auto lp = reinterpret_cast<__attribute__((address_space(3))) char*>(
      reinterpret_cast<uintptr_t>(l));
  __builtin_amdgcn_global_load_lds(gp, lp, 16, 0, 0);
}

// ---------------- cast fp32 -> bf16 (vectorized) ---------------------------
__global__ void cast_bf16(const float* __restrict__ in, u16* __restrict__ out, int n4) {
  int i = blockIdx.x * 256 + threadIdx.x;
  if (i < n4) {
    f32x4 v = ((const f32x4*)in)[i];
    u16x4 r;
    r[0] = f2bf(v[0]); r[1] = f2bf(v[1]); r[2] = f2bf(v[2]); r[3] = f2bf(v[3]);
    ((u16x4*)out)[i] = r;
  }
}

// ---------------- cast + transpose: W[K][N] fp32 -> Wt[N][K] bf16 ----------
__global__ void castT(const float* __restrict__ W, u16* __restrict__ Wt, int Kd, int Nd) {
  __shared__ float t[32][33];
  const int tn = blockIdx.x * 32, tk = blockIdx.y * 32;
  const int tx = threadIdx.x & 31, ty = threadIdx.x >> 5;
#pragma unroll
  for (int i = 0; i < 4; ++i) {
    int r = ty + i * 8;
    t[r][tx] = W[(size_t)(tk + r) * Nd + tn + tx];
  }
  __syncthreads();
#pragma unroll
  for (int i = 0; i < 4; ++i) {
    int r = ty + i * 8;
    Wt[(size_t)(tn + r) * Kd + tk + tx] = f2bf(t[tx][r]);
  }
}

// ---------------- GEMM: C[M][N] = A[M][K] * Bt[N][K]^T + bias --------------
// 128x128 tile, BK=32, 4 waves (2x2), each wave 64x64 = 4x4 fragments.
// m97 structure: global_load_lds width-16 staging, 2 barriers per K-step.
template <int OUT_BF16>
__global__ __launch_bounds__(256, 2) void gemm_bt(
    const u16* __restrict__ A, const u16* __restrict__ Bt,
    const float* __restrict__ bias, void* __restrict__ Cv, int N, int Kd) {
  __shared__ alignas(16) u16 As[128 * 32];
  __shared__ alignas(16) u16 Bs[128 * 32];
  const int tid = threadIdx.x;
  const int w = tid >> 6, lane = tid & 63;
  const int lrow = lane & 15, kg = lane >> 4;
  const int wr = w >> 1, wc = w & 1;
  const long arow0 = (long)blockIdx.y * 128;
  const long brow0 = (long)blockIdx.x * 128;

  // staging assignment: chunk (w*2+it) of 1024B; HW scatters lane*16B
  const int e0 = (w * 2) * 512 + lane * 8;   // element offset in tile image
  const int e1 = e0 + 512;
  const u16* Ag0 = A + (arow0 + (e0 >> 5)) * Kd + (e0 & 31);
  const u16* Ag1 = A + (arow0 + (e1 >> 5)) * Kd + (e1 & 31);
  const u16* Bg0 = Bt + (brow0 + (e0 >> 5)) * Kd + (e0 & 31);
  const u16* Bg1 = Bt + (brow0 + (e1 >> 5)) * Kd + (e1 & 31);
  u16* Al = As + (w * 2) * 512;
  u16* Bl = Bs + (w * 2) * 512;

  f32x4 acc[4][4];
#pragma unroll
  for (int m = 0; m < 4; ++m)
#pragma unroll
    for (int n = 0; n < 4; ++n) acc[m][n] = (f32x4){0.f, 0.f, 0.f, 0.f};

  for (int k0 = 0; k0 < Kd; k0 += 32) {
    __syncthreads();
    gld_lds16(Ag0 + k0, Al);
    gld_lds16(Ag1 + k0, Al + 512);
    gld_lds16(Bg0 + k0, Bl);
    gld_lds16(Bg1 + k0, Bl + 512);
    __syncthreads();
    s16x8 af[4], bfr[4];
#pragma unroll
    for (int m = 0; m < 4; ++m)
      af[m] = *(const s16x8*)(As + (wr * 64 + m * 16 + lrow) * 32 + kg * 8);
#pragma unroll
    for (int n = 0; n < 4; ++n)
      bfr[n] = *(const s16x8*)(Bs + (wc * 64 + n * 16 + lrow) * 32 + kg * 8);
#pragma unroll
    for (int m = 0; m < 4; ++m)
#pragma unroll
      for (int n = 0; n < 4; ++n)
        acc[m][n] = __builtin_amdgcn_mfma_f32_16x16x32_bf16(af[m], bfr[n], acc[m][n], 0, 0, 0);
  }

  // epilogue: C/D layout col=lane&15, row=(lane>>4)*4+j
#pragma unroll
  for (int m = 0; m < 4; ++m) {
    const long r0 = arow0 + wr * 64 + m * 16 + kg * 4;
#pragma unroll
    for (int n = 0; n < 4; ++n) {
      const long c = brow0 + wc * 64 + n * 16 + lrow;
      const float bv = bias[c];
#pragma unroll
      for (int j = 0; j < 4; ++j) {
        const float val = acc[m][n][j] + bv;
        if (OUT_BF16)
          ((u16*)Cv)[(r0 + j) * N + c] = f2bf(val);
        else
          ((float*)Cv)[(r0 + j) * N + c] = val;
      }
    }
  }
}

// ---------------- Flash attention (causal, GQA) ----------------------------
// grid = (T/64, B*H). 4 waves/block, wave w owns Q rows [qt*64+w*16, +16),
// full HD=128 output. KV tiles of 64. K read from global (L2-served),
// V staged transposed in LDS, P through per-wave padded LDS.
__global__ __launch_bounds__(256, 2) void attn_kernel(
    const u16* __restrict__ Q, const u16* __restrict__ Kp,
    const u16* __restrict__ Vp, u16* __restrict__ O) {
  const int qt = blockIdx.x;
  const int bh = blockIdx.y;
  const int b = bh >> 5, h = bh & 31, g = h >> 2;   // H=32, REP=4
  const int tid = threadIdx.x, w = tid >> 6, lane = tid & 63;
  const int lrow = lane & 15, kg = lane >> 4;

  __shared__ alignas(16) u16 Vt[128][72];        // V^T, padded (+8) rows
  __shared__ alignas(16) u16 Pl[4][16][72];      // per-wave P, padded

  // Q fragments (A-operand): row = lane&15, k = ks*32 + kg*8 .. +8
  const u16* Qb = Q + ((size_t)b * Tc + (size_t)qt * 64 + w * 16 + lrow) * Dc + h * 128;
  s16x8 qf[4];
#pragma unroll
  for (int ks = 0; ks < 4; ++ks) qf[ks] = *(const s16x8*)(Qb + ks * 32 + kg * 8);

  const u16* Kb = Kp + (size_t)b * Tc * GHDc + g * 128;
  const u16* Vb = Vp + (size_t)b * Tc * GHDc + g * 128;

  f32x4 o[8];
#pragma unroll
  for (int n = 0; n < 8; ++n) o[n] = (f32x4){0.f, 0.f, 0.f, 0.f};
  float mrow[4], lsum[4];
#pragma unroll
  for (int j = 0; j < 4; ++j) { mrow[j] = -1e30f; lsum[j] = 0.f; }

  const float sc = 0.08838834764831845f;   // 1/sqrt(128)

  for (int kt = 0; kt <= qt; ++kt) {
    // --- stage V-tile transposed: Vt[hd][kv] ---
    __syncthreads();
#pragma unroll
    for (int i = 0; i < 4; ++i) {
      int c = tid * 4 + i;                  // 1024 chunks of 8 elems
      int kv = c >> 4, hd = (c & 15) * 8;
      s16x8 v = *(const s16x8*)(Vb + ((size_t)kt * 64 + kv) * GHDc + hd);
#pragma unroll
      for (int e = 0; e < 8; ++e) Vt[hd + e][kv] = (u16)v[e];
    }
    __syncthreads();

    // --- S = Q K^T : B-operand col = K row (kv), k contiguous in HD ---
    f32x4 s[4];
#pragma unroll
    for (int n = 0; n < 4; ++n) s[n] = (f32x4){0.f, 0.f, 0.f, 0.f};
#pragma unroll
    for (int n = 0; n < 4; ++n) {
      const u16* Kr = Kb + ((size_t)kt * 64 + n * 16 + lrow) * GHDc;
#pragma unroll
      for (int ks = 0; ks < 4; ++ks) {
        s16x8 kf = *(const s16x8*)(Kr + ks * 32 + kg * 8);
        s[n] = __builtin_amdgcn_mfma_f32_16x16x32_bf16(qf[ks], kf, s[n], 0, 0, 0);
      }
    }

    // --- scale + causal mask (diagonal tile only) ---
    const int qpos = qt * 64 + w * 16 + kg * 4;   // + j
    if (kt == qt) {
#pragma unroll
      for (int n = 0; n < 4; ++n) {
        const int kvpos = kt * 64 + n * 16 + lrow;
#pragma unroll
        for (int j = 0; j < 4; ++j)
          s[n][j] = (kvpos > qpos + j) ? -1e30f : s[n][j] * sc;
      }
    } else {
#pragma unroll
      for (int n = 0; n < 4; ++n)
#pragma unroll
        for (int j = 0; j < 4; ++j) s[n][j] *= sc;
    }

    // --- online softmax, rows distributed as (kg*4+j), 16-lane reduce ---
#pragma unroll
    for (int j = 0; j < 4; ++j) {
      float rm = fmaxf(fmaxf(s[0][j], s[1][j]), fmaxf(s[2][j], s[3][j]));
      rm = fmaxf(rm, __shfl_xor(rm, 1));
      rm = fmaxf(rm, __shfl_xor(rm, 2));
      rm = fmaxf(rm, __shfl_xor(rm, 4));
      rm = fmaxf(rm, __shfl_xor(rm, 8));
      const float mnew = fmaxf(mrow[j], rm);
      const float scale = __expf(mrow[j] - mnew);
      float rs = 0.f;
#pragma unroll
      for (int n = 0; n < 4; ++n) {
        float p = __expf(s[n][j] - mnew);
        s[n][j] = p;
        rs += p;
      }
      rs += __shfl_xor(rs, 1);
      rs += __shfl_xor(rs, 2);
      rs += __shfl_xor(rs, 4);
      rs += __shfl_xor(rs, 8);
      lsum[j] = lsum[j] * scale + rs;
      mrow[j] = mnew;
#pragma unroll
      for (int n = 0; n < 8; ++n) o[n][j] *= scale;
    }

    // --- P -> LDS (redistribute to A-operand layout) ---
#pragma unroll
    for (int n = 0; n < 4; ++n)
#pragma unroll
      for (int j = 0; j < 4; ++j)
        Pl[w][kg * 4 + j][n * 16 + lrow] = f2bf(s[n][j]);
    asm volatile("s_waitcnt lgkmcnt(0)" ::: "memory");

    // --- O += P V ---
#pragma unroll
    for (int ks2 = 0; ks2 < 2; ++ks2) {
      s16x8 pa = *(const s16x8*)(&Pl[w][lrow][ks2 * 32 + kg * 8]);
#pragma unroll
      for (int n = 0; n < 8; ++n) {
        s16x8 vb = *(const s16x8*)(&Vt[n * 16 + lrow][ks2 * 32 + kg * 8]);
        o[n] = __builtin_amdgcn_mfma_f32_16x16x32_bf16(pa, vb, o[n], 0, 0, 0);
      }
    }
  }

  // --- normalize + write ---
  u16* Ob = O + ((size_t)b * Tc + (size_t)qt * 64 + w * 16) * Dc + h * 128;
#pragma unroll
  for (int j = 0; j < 4; ++j) {
    const float inv = 1.f / lsum[j];
    const int r = kg * 4 + j;
#pragma unroll
    for (int n = 0; n < 8; ++n)
      Ob[(size_t)r * Dc + n * 16 + lrow] = f2bf(o[n][j] * inv);
  }
}

// ---------------------------------------------------------------------------
extern "C" void kernel_launch(void* const* d_in, const int* in_sizes, int n_in,
                              void* d_out, int out_size, void* d_ws, size_t ws_size,
                              hipStream_t stream) {
  (void)in_sizes; (void)n_in; (void)out_size; (void)ws_size;
  const float* x  = (const float*)d_in[0];
  // d_in[1] = mask (static causal -> hardcoded)
  const float* Wq = (const float*)d_in[2];
  const float* bq = (const float*)d_in[3];
  const float* Wk = (const float*)d_in[4];
  const float* bk = (const float*)d_in[5];
  const float* Wv = (const float*)d_in[6];
  const float* bv = (const float*)d_in[7];
  const float* Wo = (const float*)d_in[8];
  const float* bo = (const float*)d_in[9];
  float* out = (float*)d_out;

  char* ws = (char*)d_ws;
  // layout (bytes):
  //   [0,   32M) xb  (bf16 x)          -> later reused as attention output AOb
  //   [32M, 64M) Qb
  //   [64M, 96M) Wqt                   -> later reused as Kb (8M) + Vb (8M)
  //   [96M,128M) Wot
  //   [128M,136M) Wkt
  //   [136M,144M) Wvt                  total ~151MB
  u16* xb  = (u16*)(ws);
  u16* Qb  = (u16*)(ws + 33554432);
  u16* Wqt = (u16*)(ws + 67108864);
  u16* Wot = (u16*)(ws + 100663296);
  u16* Wkt = (u16*)(ws + 134217728);
  u16* Wvt = (u16*)(ws + 142606336);
  u16* Kb  = (u16*)(ws + 67108864);   // aliases Wqt (dead after Q-proj)
  u16* Vb  = (u16*)(ws + 75497472);
  u16* AOb = xb;                      // aliases xb (dead after V-proj)

  const int M = Bc * Tc;  // 4096

  // casts
  cast_bf16<<<(M * Dc / 4 + 255) / 256, 256, 0, stream>>>(x, xb, M * Dc / 4);
  castT<<<dim3(Dc / 32, Dc / 32), 256, 0, stream>>>(Wq, Wqt, Dc, Dc);
  castT<<<dim3(GHDc / 32, Dc / 32), 256, 0, stream>>>(Wk, Wkt, Dc, GHDc);
  castT<<<dim3(GHDc / 32, Dc / 32), 256, 0, stream>>>(Wv, Wvt, Dc, GHDc);
  castT<<<dim3(Dc / 32, Dc / 32), 256, 0, stream>>>(Wo, Wot, Dc, Dc);

  // projections
  gemm_bt<1><<<dim3(Dc / 128, M / 128), 256, 0, stream>>>(xb, Wqt, bq, Qb, Dc, Dc);
  gemm_bt<1><<<dim3(GHDc / 128, M / 128), 256, 0, stream>>>(xb, Wkt, bk, Kb, GHDc, Dc);
  gemm_bt<1><<<dim3(GHDc / 128, M / 128), 256, 0, stream>>>(xb, Wvt, bv, Vb, GHDc, Dc);

  // attention (writes AOb = xb region; x dead by now)
  attn_kernel<<<dim3(Tc / 64, Bc * Hc), 256, 0, stream>>>(Qb, Kb, Vb, AOb);

  // output projection (fp32 out + bias)
  gemm_bt<0><<<dim3(Dc / 128, M / 128), 256, 0, stream>>>(AOb, Wot, bo, out, Dc, Dc);
}

// Round 3
// 866.742 us; speedup vs baseline: 1.4228x; 1.4228x over previous
//
#include <hip/hip_runtime.h>

// ---------------------------------------------------------------------------
// GQA forward: out = softmax_causal((xWq)(xWk)^T/sqrt(128)) (xWv) Wo + biases
// B=2, T=2048, D=4096, H=32, G=8, HD=128, REP=4
// R2: attn rewrite — causal pair-scheduling, K in LDS (swizzled gld_lds),
// swizzled Vt/Pl (stride 64 + chunk-XOR), V reg-prefetch with raw barriers
// + counted vmcnt. K/V projections fused into one N=2048 GEMM.
// ---------------------------------------------------------------------------

typedef unsigned short u16;
typedef unsigned int u32;
using s16x8 = __attribute__((ext_vector_type(8))) short;   // 8 x bf16 (4 VGPR)
using f32x4 = __attribute__((ext_vector_type(4))) float;   // MFMA C/D
using u16x4 = __attribute__((ext_vector_type(4))) u16;

#define Bc   2
#define Tc   2048
#define Dc   4096
#define GHDc 1024   // G*HD
#define KVS  2048   // fused KV row stride (u16)
#define Hc   32
#define NT   32     // T/64 kv/q tiles

__device__ __forceinline__ u16 f2bf(float x) {
  unsigned b = __float_as_uint(x);
  return (u16)((b + 0x7FFFu + ((b >> 16) & 1u)) >> 16);   // RTNE
}

__device__ __forceinline__ void gld_lds16(const void* g, void* l) {
  auto gp = reinterpret_cast<const __attribute__((address_space(1))) char*>(
      reinterpret_cast<uintptr_t>(g));
  auto lp = reinterpret_cast<__attribute__((address_space(3))) char*>(
      reinterpret_cast<uintptr_t>(l));
  __builtin_amdgcn_global_load_lds(gp, lp, 16, 0, 0);
}

#define MEMFENCE asm volatile("" ::: "memory")

// ---------------- cast fp32 -> bf16 (vectorized) ---------------------------
__global__ void cast_bf16(const float* __restrict__ in, u16* __restrict__ out, int n4) {
  int i = blockIdx.x * 256 + threadIdx.x;
  if (i < n4) {
    f32x4 v = ((const f32x4*)in)[i];
    u16x4 r;
    r[0] = f2bf(v[0]); r[1] = f2bf(v[1]); r[2] = f2bf(v[2]); r[3] = f2bf(v[3]);
    ((u16x4*)out)[i] = r;
  }
}

// ---------------- concat bias [bk | bv] ------------------------------------
__global__ void concat_bias(const float* __restrict__ a, const float* __restrict__ b,
                            float* __restrict__ o) {
  int i = blockIdx.x * 256 + threadIdx.x;
  if (i < 2048) o[i] = (i < 1024) ? a[i] : b[i - 1024];
}

// ---------------- cast + transpose: W[K][N] fp32 -> Wt[N][K] bf16 ----------
__global__ void castT(const float* __restrict__ W, u16* __restrict__ Wt, int Kd, int Nd) {
  __shared__ float t[32][33];
  const int tn = blockIdx.x * 32, tk = blockIdx.y * 32;
  const int tx = threadIdx.x & 31, ty = threadIdx.x >> 5;
#pragma unroll
  for (int i = 0; i < 4; ++i) {
    int r = ty + i * 8;
    t[r][tx] = W[(size_t)(tk + r) * Nd + tn + tx];
  }
  __syncthreads();
#pragma unroll
  for (int i = 0; i < 4; ++i) {
    int r = ty + i * 8;
    Wt[(size_t)(tn + r) * Kd + tk + tx] = f2bf(t[tx][r]);
  }
}

// ---------------- GEMM: C[M][N] = A[M][K] * Bt[N][K]^T + bias --------------
// 128x128 tile, BK=32, 4 waves (2x2), m97 structure.
template <int OUT_BF16>
__global__ __launch_bounds__(256, 2) void gemm_bt(
    const u16* __restrict__ A, const u16* __restrict__ Bt,
    const float* __restrict__ bias, void* __restrict__ Cv, int N, int Kd) {
  __shared__ alignas(16) u16 As[128 * 32];
  __shared__ alignas(16) u16 Bs[128 * 32];
  const int tid = threadIdx.x;
  const int w = tid >> 6, lane = tid & 63;
  const int lrow = lane & 15, kg = lane >> 4;
  const int wr = w >> 1, wc = w & 1;
  const long arow0 = (long)blockIdx.y * 128;
  const long brow0 = (long)blockIdx.x * 128;

  const int e0 = (w * 2) * 512 + lane * 8;
  const int e1 = e0 + 512;
  const u16* Ag0 = A + (arow0 + (e0 >> 5)) * Kd + (e0 & 31);
  const u16* Ag1 = A + (arow0 + (e1 >> 5)) * Kd + (e1 & 31);
  const u16* Bg0 = Bt + (brow0 + (e0 >> 5)) * Kd + (e0 & 31);
  const u16* Bg1 = Bt + (brow0 + (e1 >> 5)) * Kd + (e1 & 31);
  u16* Al = As + (w * 2) * 512;
  u16* Bl = Bs + (w * 2) * 512;

  f32x4 acc[4][4];
#pragma unroll
  for (int m = 0; m < 4; ++m)
#pragma unroll
    for (int n = 0; n < 4; ++n) acc[m][n] = (f32x4){0.f, 0.f, 0.f, 0.f};

  for (int k0 = 0; k0 < Kd; k0 += 32) {
    __syncthreads();
    gld_lds16(Ag0 + k0, Al);
    gld_lds16(Ag1 + k0, Al + 512);
    gld_lds16(Bg0 + k0, Bl);
    gld_lds16(Bg1 + k0, Bl + 512);
    __syncthreads();
    s16x8 af[4], bfr[4];
#pragma unroll
    for (int m = 0; m < 4; ++m)
      af[m] = *(const s16x8*)(As + (wr * 64 + m * 16 + lrow) * 32 + kg * 8);
#pragma unroll
    for (int n = 0; n < 4; ++n)
      bfr[n] = *(const s16x8*)(Bs + (wc * 64 + n * 16 + lrow) * 32 + kg * 8);
#pragma unroll
    for (int m = 0; m < 4; ++m)
#pragma unroll
      for (int n = 0; n < 4; ++n)
        acc[m][n] = __builtin_amdgcn_mfma_f32_16x16x32_bf16(af[m], bfr[n], acc[m][n], 0, 0, 0);
  }

#pragma unroll
  for (int m = 0; m < 4; ++m) {
    const long r0 = arow0 + wr * 64 + m * 16 + kg * 4;
#pragma unroll
    for (int n = 0; n < 4; ++n) {
      const long c = brow0 + wc * 64 + n * 16 + lrow;
      const float bv = bias[c];
#pragma unroll
      for (int j = 0; j < 4; ++j) {
        const float val = acc[m][n][j] + bv;
        if (OUT_BF16)
          ((u16*)Cv)[(r0 + j) * N + c] = f2bf(val);
        else
          ((float*)Cv)[(r0 + j) * N + c] = val;
      }
    }
  }
}

// ---------------- Flash attention (causal, GQA), pair-scheduled ------------
// grid = (NT/2, B*H). Block p handles q-tiles {p, NT-1-p} (uniform work).
// 4 waves, wave w owns 16 Q rows. K staged in LDS via swizzled gld_lds;
// V prefetched to regs then written transposed+swizzled; P swizzled LDS.
// All LDS layouts: stride 64 u16 rows, 16B-chunk XOR swizzle (chunk ^= row&7).
__global__ __launch_bounds__(256, 3) void attn_kernel(
    const u16* __restrict__ Q, const u16* __restrict__ KV, u16* __restrict__ O) {
  const int p = blockIdx.x;
  const int bh = blockIdx.y;
  const int b = bh >> 5, h = bh & 31, g = h >> 2;
  const int tid = threadIdx.x, w = tid >> 6, lane = tid & 63;
  const int lrow = lane & 15, kg = lane >> 4;

  __shared__ alignas(16) u16 Ks[64 * 128];   // swizzled K rows (16 KB)
  __shared__ alignas(16) u16 Vt[128 * 64];   // swizzled V^T   (16 KB)
  __shared__ alignas(16) u16 Pl[4][16 * 64]; // per-wave P     (8 KB)

  const u16* Kb = KV + (size_t)b * Tc * KVS + g * 128;
  const u16* Vb = Kb + GHDc;                 // V half of fused row

  // V-prefetch assignment: thread covers kv {kv0,kv0+1} x hd-chunks {hc0,hc0+1}
  const int kv0 = (tid & 31) * 2;
  const int hc0 = (tid >> 5) * 2;

  const float sc = 0.08838834764831845f;     // 1/sqrt(128)

#pragma unroll 1
  for (int ph = 0; ph < 2; ++ph) {
    const int qt = ph ? (NT - 1 - p) : p;

    // Q fragments (A-operand)
    const u16* Qb = Q + ((size_t)b * Tc + (size_t)qt * 64 + w * 16 + lrow) * Dc + h * 128;
    s16x8 qf[4];
#pragma unroll
    for (int ks = 0; ks < 4; ++ks) qf[ks] = *(const s16x8*)(Qb + ks * 32 + kg * 8);

    f32x4 o[8];
#pragma unroll
    for (int n = 0; n < 8; ++n) o[n] = (f32x4){0.f, 0.f, 0.f, 0.f};
    float mrow[4], lsum[4];
#pragma unroll
    for (int j = 0; j < 4; ++j) { mrow[j] = -1e30f; lsum[j] = 0.f; }

#pragma unroll 1
    for (int kt = 0; kt <= qt; ++kt) {
      MEMFENCE;
      __builtin_amdgcn_s_barrier();          // #1: prev-iter LDS reads done
      MEMFENCE;

      // --- stage K(kt) via swizzled global_load_lds (16 KB) ---
      const u16* Kt = Kb + (size_t)kt * 64 * KVS;
#pragma unroll
      for (int i = 0; i < 4; ++i) {
        const int seg = w * 4 + i;                 // wave-uniform
        const int kv = seg * 4 + (lane >> 4);      // lane>>4 in 0..3
        const int lchunk = (lane & 15) ^ (kv & 7); // pre-swizzled source chunk
        gld_lds16(Kt + (size_t)kv * KVS + lchunk * 8, (char*)Ks + seg * 1024);
      }
      MEMFENCE;
      // --- prefetch V(kt) to regs (latency hides under QK^T+softmax) ---
      const u16* Vtile = Vb + (size_t)kt * 64 * KVS;
      s16x8 vr[4];
#pragma unroll
      for (int i = 0; i < 4; ++i) {
        const int kv = kv0 + (i & 1), hc = hc0 + (i >> 1);
        vr[i] = *(const s16x8*)(Vtile + (size_t)kv * KVS + hc * 8);
      }
      MEMFENCE;
      asm volatile("s_waitcnt vmcnt(4)" ::: "memory");  // K staged (V still in flight)
      __builtin_amdgcn_s_barrier();          // #2: K visible to all waves
      MEMFENCE;

      // --- S = Q K^T from swizzled Ks ---
      f32x4 s[4];
#pragma unroll
      for (int n = 0; n < 4; ++n) s[n] = (f32x4){0.f, 0.f, 0.f, 0.f};
#pragma unroll
      for (int n = 0; n < 4; ++n) {
        const int r = n * 16 + lrow;
#pragma unroll
        for (int ks = 0; ks < 4; ++ks) {
          const int pch = (ks * 4 + kg) ^ (lrow & 7);
          s16x8 kf = *(const s16x8*)(Ks + r * 128 + pch * 8);
          s[n] = __builtin_amdgcn_mfma_f32_16x16x32_bf16(qf[ks], kf, s[n], 0, 0, 0);
        }
      }

      // --- scale + causal mask (diagonal tile only) ---
      const int qpos = qt * 64 + w * 16 + kg * 4;
      if (kt == qt) {
#pragma unroll
        for (int n = 0; n < 4; ++n) {
          const int kvpos = kt * 64 + n * 16 + lrow;
#pragma unroll
          for (int j = 0; j < 4; ++j)
            s[n][j] = (kvpos > qpos + j) ? -1e30f : s[n][j] * sc;
        }
      } else {
#pragma unroll
        for (int n = 0; n < 4; ++n)
#pragma unroll
          for (int j = 0; j < 4; ++j) s[n][j] *= sc;
      }

      // --- online softmax (rows kg*4+j, 16-lane shuffle reduce) ---
#pragma unroll
      for (int j = 0; j < 4; ++j) {
        float rm = fmaxf(fmaxf(s[0][j], s[1][j]), fmaxf(s[2][j], s[3][j]));
        rm = fmaxf(rm, __shfl_xor(rm, 1));
        rm = fmaxf(rm, __shfl_xor(rm, 2));
        rm = fmaxf(rm, __shfl_xor(rm, 4));
        rm = fmaxf(rm, __shfl_xor(rm, 8));
        const float mnew = fmaxf(mrow[j], rm);
        const float scale = __expf(mrow[j] - mnew);
        float rs = 0.f;
#pragma unroll
        for (int n = 0; n < 4; ++n) {
          float pv = __expf(s[n][j] - mnew);
          s[n][j] = pv;
          rs += pv;
        }
        rs += __shfl_xor(rs, 1);
        rs += __shfl_xor(rs, 2);
        rs += __shfl_xor(rs, 4);
        rs += __shfl_xor(rs, 8);
        lsum[j] = lsum[j] * scale + rs;
        mrow[j] = mnew;
#pragma unroll
        for (int n = 0; n < 8; ++n) o[n][j] *= scale;
      }

      // --- write V^T (paired b32, swizzled) ---
      // element (hd, kv) at u16 off: hd*64 + ((kv>>3)^(hd&7))*8 + (kv&7)
#pragma unroll
      for (int a = 0; a < 2; ++a) {
        const int hd0 = (hc0 + a) * 8;
#pragma unroll
        for (int e = 0; e < 8; ++e) {
          const int hd = hd0 + e;
          const u32 pk = (u32)(u16)vr[a * 2 + 0][e] | ((u32)(u16)vr[a * 2 + 1][e] << 16);
          *(u32*)(Vt + hd * 64 + (((kv0 >> 3) ^ (hd & 7)) * 8) + (kv0 & 7)) = pk;
        }
      }
      // --- write P (swizzled) ---
      // element (q, kv) at u16 off: q*64 + ((kv>>3)^(q&7))*8 + (kv&7)
      u16* Pw = Pl[w];
#pragma unroll
      for (int n = 0; n < 4; ++n)
#pragma unroll
        for (int j = 0; j < 4; ++j) {
          const int q = kg * 4 + j;
          const int kv = n * 16 + lrow;
          Pw[q * 64 + (((kv >> 3) ^ (q & 7)) * 8) + (kv & 7)] = f2bf(s[n][j]);
        }
      asm volatile("s_waitcnt lgkmcnt(0)" ::: "memory");
      __builtin_amdgcn_s_barrier();          // #3: Vt/Pl visible
      MEMFENCE;

      // --- O += P V ---
#pragma unroll
      for (int ks2 = 0; ks2 < 2; ++ks2) {
        const int pch = (ks2 * 4 + kg) ^ (lrow & 7);
        s16x8 pa = *(const s16x8*)(Pw + lrow * 64 + pch * 8);
#pragma unroll
        for (int n = 0; n < 8; ++n) {
          const int hd = n * 16 + lrow;
          s16x8 vb = *(const s16x8*)(Vt + hd * 64 + pch * 8);
          o[n] = __builtin_amdgcn_mfma_f32_16x16x32_bf16(pa, vb, o[n], 0, 0, 0);
        }
      }
    }

    // --- normalize + write ---
    u16* Ob = O + ((size_t)b * Tc + (size_t)qt * 64 + w * 16) * Dc + h * 128;
#pragma unroll
    for (int j = 0; j < 4; ++j) {
      const float inv = 1.f / lsum[j];
      const int r = kg * 4 + j;
#pragma unroll
      for (int n = 0; n < 8; ++n)
        Ob[(size_t)r * Dc + n * 16 + lrow] = f2bf(o[n][j] * inv);
    }
  }
}

// ---------------------------------------------------------------------------
extern "C" void kernel_launch(void* const* d_in, const int* in_sizes, int n_in,
                              void* d_out, int out_size, void* d_ws, size_t ws_size,
                              hipStream_t stream) {
  (void)in_sizes; (void)n_in; (void)out_size; (void)ws_size;
  const float* x  = (const float*)d_in[0];
  const float* Wq = (const float*)d_in[2];
  const float* bq = (const float*)d_in[3];
  const float* Wk = (const float*)d_in[4];
  const float* bk = (const float*)d_in[5];
  const float* Wv = (const float*)d_in[6];
  const float* bv = (const float*)d_in[7];
  const float* Wo = (const float*)d_in[8];
  const float* bo = (const float*)d_in[9];
  float* out = (float*)d_out;

  char* ws = (char*)d_ws;
  // layout (bytes):
  //   [0,  32M) xb (bf16 x)      -> reused as attn output AOb
  //   [32M,64M) Qb
  //   [64M,96M) Wqt              -> reused as KVb (16M, dead after Q-proj)
  //   [96M,112M) WKVt (2048x4096 bf16)
  //   [112M,144M) Wot
  //   [144M,+8K) bkv             total ~144MB
  u16* xb   = (u16*)(ws);
  u16* Qb   = (u16*)(ws + 33554432);
  u16* Wqt  = (u16*)(ws + 67108864);
  u16* WKVt = (u16*)(ws + 100663296);
  u16* Wot  = (u16*)(ws + 117440512);
  float* bkv = (float*)(ws + 150994944);
  u16* KVb  = (u16*)(ws + 67108864);   // aliases Wqt
  u16* AOb  = xb;                      // aliases xb

  const int M = Bc * Tc;  // 4096

  // casts + bias concat
  cast_bf16<<<(M * Dc / 4 + 255) / 256, 256, 0, stream>>>(x, xb, M * Dc / 4);
  castT<<<dim3(Dc / 32, Dc / 32), 256, 0, stream>>>(Wq, Wqt, Dc, Dc);
  castT<<<dim3(GHDc / 32, Dc / 32), 256, 0, stream>>>(Wk, WKVt, Dc, GHDc);
  castT<<<dim3(GHDc / 32, Dc / 32), 256, 0, stream>>>(Wv, WKVt + (size_t)GHDc * Dc, Dc, GHDc);
  castT<<<dim3(Dc / 32, Dc / 32), 256, 0, stream>>>(Wo, Wot, Dc, Dc);
  concat_bias<<<8, 256, 0, stream>>>(bk, bv, bkv);

  // projections
  gemm_bt<1><<<dim3(Dc / 128, M / 128), 256, 0, stream>>>(xb, Wqt, bq, Qb, Dc, Dc);
  gemm_bt<1><<<dim3(KVS / 128, M / 128), 256, 0, stream>>>(xb, WKVt, bkv, KVb, KVS, Dc);

  // attention (pair-scheduled causal)
  attn_kernel<<<dim3(NT / 2, Bc * Hc), 256, 0, stream>>>(Qb, KVb, AOb);

  // output projection (fp32 out + bias)
  gemm_bt<0><<<dim3(Dc / 128, M / 128), 256, 0, stream>>>(AOb, Wot, bo, out, Dc, Dc);
}

// Round 9
// 800.471 us; speedup vs baseline: 1.5406x; 1.0828x over previous
//
#include <hip/hip_runtime.h>

// ---------------------------------------------------------------------------
// GQA forward: out = softmax_causal((xWq)(xWk)^T/sqrt(128)) (xWv) Wo + biases
// B=2, T=2048, D=4096, H=32, G=8, HD=128, REP=4
// R4 (5th resubmit after infra timeouts): (a) 256x256 deep-pipelined GEMM
// (counted-vmcnt 4-phase/K-tile, K-half split staging, chunk-XOR swizzle) for
// Q-proj and O-proj; (b) attn K double-buffer + defer-max + exp2 softmax.
// ---------------------------------------------------------------------------

typedef unsigned short u16;
typedef unsigned int u32;
using s16x8 = __attribute__((ext_vector_type(8))) short;   // 8 x bf16 (4 VGPR)
using f32x4 = __attribute__((ext_vector_type(4))) float;   // MFMA C/D
using u16x4 = __attribute__((ext_vector_type(4))) u16;

#define Bc   2
#define Tc   2048
#define Dc   4096
#define GHDc 1024   // G*HD
#define KVS  2048   // fused KV row stride (u16)
#define Hc   32
#define NT   32     // T/64 kv/q tiles

__device__ __forceinline__ u16 f2bf(float x) {
  unsigned b = __float_as_uint(x);
  return (u16)((b + 0x7FFFu + ((b >> 16) & 1u)) >> 16);   // RTNE
}

__device__ __forceinline__ void gld_lds16(const void* g, void* l) {
  auto gp = reinterpret_cast<const __attribute__((address_space(1))) char*>(
      reinterpret_cast<uintptr_t>(g));
  auto lp = reinterpret_cast<__attribute__((address_space(3))) char*>(
      reinterpret_cast<uintptr_t>(l));
  __builtin_amdgcn_global_load_lds(gp, lp, 16, 0, 0);
}

#define MEMFENCE asm volatile("" ::: "memory")
#define BAR()    do { MEMFENCE; __builtin_amdgcn_s_barrier(); MEMFENCE; } while (0)
#define VMCNT(n) asm volatile("s_waitcnt vmcnt(" #n ")" ::: "memory")
#define LGKM0()  asm volatile("s_waitcnt lgkmcnt(0)" ::: "memory")

// ---------------- cast fp32 -> bf16 (vectorized) ---------------------------
__global__ void cast_bf16(const float* __restrict__ in, u16* __restrict__ out, int n4) {
  int i = blockIdx.x * 256 + threadIdx.x;
  if (i < n4) {
    f32x4 v = ((const f32x4*)in)[i];
    u16x4 r;
    r[0] = f2bf(v[0]); r[1] = f2bf(v[1]); r[2] = f2bf(v[2]); r[3] = f2bf(v[3]);
    ((u16x4*)out)[i] = r;
  }
}

// ---------------- concat bias [bk | bv] ------------------------------------
__global__ void concat_bias(const float* __restrict__ a, const float* __restrict__ b,
                            float* __restrict__ o) {
  int i = blockIdx.x * 256 + threadIdx.x;
  if (i < 2048) o[i] = (i < 1024) ? a[i] : b[i - 1024];
}

// ---------------- cast + transpose: W[K][N] fp32 -> Wt[N][K] bf16 ----------
__global__ void castT(const float* __restrict__ W, u16* __restrict__ Wt, int Kd, int Nd) {
  __shared__ float t[32][33];
  const int tn = blockIdx.x * 32, tk = blockIdx.y * 32;
  const int tx = threadIdx.x & 31, ty = threadIdx.x >> 5;
#pragma unroll
  for (int i = 0; i < 4; ++i) {
    int r = ty + i * 8;
    t[r][tx] = W[(size_t)(tk + r) * Nd + tn + tx];
  }
  __syncthreads();
#pragma unroll
  for (int i = 0; i < 4; ++i) {
    int r = ty + i * 8;
    Wt[(size_t)(tn + r) * Kd + tk + tx] = f2bf(t[tx][r]);
  }
}

// ---------------- m97 GEMM (kept for KV-proj, N=2048) ----------------------
template <int OUT_BF16>
__global__ __launch_bounds__(256, 2) void gemm_bt(
    const u16* __restrict__ A, const u16* __restrict__ Bt,
    const float* __restrict__ bias, void* __restrict__ Cv, int N, int Kd) {
  __shared__ alignas(16) u16 As[128 * 32];
  __shared__ alignas(16) u16 Bs[128 * 32];
  const int tid = threadIdx.x;
  const int w = tid >> 6, lane = tid & 63;
  const int lrow = lane & 15, kg = lane >> 4;
  const int wr = w >> 1, wc = w & 1;
  const long arow0 = (long)blockIdx.y * 128;
  const long brow0 = (long)blockIdx.x * 128;

  const int e0 = (w * 2) * 512 + lane * 8;
  const int e1 = e0 + 512;
  const u16* Ag0 = A + (arow0 + (e0 >> 5)) * Kd + (e0 & 31);
  const u16* Ag1 = A + (arow0 + (e1 >> 5)) * Kd + (e1 & 31);
  const u16* Bg0 = Bt + (brow0 + (e0 >> 5)) * Kd + (e0 & 31);
  const u16* Bg1 = Bt + (brow0 + (e1 >> 5)) * Kd + (e1 & 31);
  u16* Al = As + (w * 2) * 512;
  u16* Bl = Bs + (w * 2) * 512;

  f32x4 acc[4][4];
#pragma unroll
  for (int m = 0; m < 4; ++m)
#pragma unroll
    for (int n = 0; n < 4; ++n) acc[m][n] = (f32x4){0.f, 0.f, 0.f, 0.f};

  for (int k0 = 0; k0 < Kd; k0 += 32) {
    __syncthreads();
    gld_lds16(Ag0 + k0, Al);
    gld_lds16(Ag1 + k0, Al + 512);
    gld_lds16(Bg0 + k0, Bl);
    gld_lds16(Bg1 + k0, Bl + 512);
    __syncthreads();
    s16x8 af[4], bfr[4];
#pragma unroll
    for (int m = 0; m < 4; ++m)
      af[m] = *(const s16x8*)(As + (wr * 64 + m * 16 + lrow) * 32 + kg * 8);
#pragma unroll
    for (int n = 0; n < 4; ++n)
      bfr[n] = *(const s16x8*)(Bs + (wc * 64 + n * 16 + lrow) * 32 + kg * 8);
#pragma unroll
    for (int m = 0; m < 4; ++m)
#pragma unroll
      for (int n = 0; n < 4; ++n)
        acc[m][n] = __builtin_amdgcn_mfma_f32_16x16x32_bf16(af[m], bfr[n], acc[m][n], 0, 0, 0);
  }

#pragma unroll
  for (int m = 0; m < 4; ++m) {
    const long r0 = arow0 + wr * 64 + m * 16 + kg * 4;
#pragma unroll
    for (int n = 0; n < 4; ++n) {
      const long c = brow0 + wc * 64 + n * 16 + lrow;
      const float bv = bias[c];
#pragma unroll
      for (int j = 0; j < 4; ++j) {
        const float val = acc[m][n][j] + bv;
        if (OUT_BF16)
          ((u16*)Cv)[(r0 + j) * N + c] = f2bf(val);
        else
          ((float*)Cv)[(r0 + j) * N + c] = val;
      }
    }
  }
}

// ---------------- 256x256 deep-pipelined GEMM ------------------------------
// BK=64 split in two K-halves. 8 waves (2m x 4n), per-wave 128x64 output.
// LDS (dynamic 128KB): As[buf][half][256][32], Bs likewise. Swizzle within a
// half: element (r,k) at r*32 + ((kc ^ ((r>>1)&3))<<3) + (k&7), kc=k>>3.
// Staging: global_load_lds, 1024B groups = 16 rows x 64B, inverse-swizzled
// per-lane global source. Per K-tile, 4 phases:
//  P0: [stage Ak0(next); vmcnt(6); bar] read Ak0/Bk0 frags; 16 MFMA (ks0,m0-3)
//  P1: stage Bk0(next); read Ak0 m4-7; 16 MFMA (ks0,m4-7)
//  P2: [stage Ak1(next); vmcnt(6); bar] read Ak1/Bk1 frags; 16 MFMA (ks1,m0-3)
//  P3: stage Bk1(next); read Ak1 m4-7; 16 MFMA (ks1,m4-7)
// vmcnt(6) = 3 half-tiles x 2 loads in flight; barriers never drain loads.
template <int OUT_BF16>
__global__ __launch_bounds__(512, 2) void gemm256(
    const u16* __restrict__ A, const u16* __restrict__ Bt,
    const float* __restrict__ bias, void* __restrict__ Cv, int N, int Kd) {
  extern __shared__ u16 lds[];
  const int tid = threadIdx.x;
  const int w = tid >> 6, lane = tid & 63;
  const int lrow = lane & 15, kg = lane >> 4;
  const int wm = w >> 2, wn = w & 3;
  const long arow0 = (long)blockIdx.y * 256;
  const long brow0 = (long)blockIdx.x * 256;

  // staging: wave w covers groups {2w, 2w+1}; lane -> row l>>2, slot l&3
  const int rl = lane >> 2;
  const int skc = (lane & 3) ^ ((rl >> 1) & 3);          // source k-chunk
  const u16* aRow0 = A + (arow0 + (w * 2 + 0) * 16 + rl) * (long)Kd + skc * 8;
  const u16* aRow1 = A + (arow0 + (w * 2 + 1) * 16 + rl) * (long)Kd + skc * 8;
  const u16* bRow0 = Bt + (brow0 + (w * 2 + 0) * 16 + rl) * (long)Kd + skc * 8;
  const u16* bRow1 = Bt + (brow0 + (w * 2 + 1) * 16 + rl) * (long)Kd + skc * 8;
  const int gof0 = (w * 2 + 0) * 1024, gof1 = (w * 2 + 1) * 1024;  // bytes

#define ASP(S, h) (lds + ((S) * 2 + (h)) * 8192)
#define BSP(S, h) (lds + 32768 + ((S) * 2 + (h)) * 8192)
#define STG_A(S, h, koff) do { \
    gld_lds16(aRow0 + (koff) + (h) * 32, (char*)ASP(S, h) + gof0); \
    gld_lds16(aRow1 + (koff) + (h) * 32, (char*)ASP(S, h) + gof1); } while (0)
#define STG_B(S, h, koff) do { \
    gld_lds16(bRow0 + (koff) + (h) * 32, (char*)BSP(S, h) + gof0); \
    gld_lds16(bRow1 + (koff) + (h) * 32, (char*)BSP(S, h) + gof1); } while (0)

  // fragment LDS offsets (u16), stored chunk = kg ^ ((lrow>>1)&3)
  const int fsc = (kg ^ ((lrow >> 1) & 3)) << 3;
  int aoffs[8], boffs[4];
#pragma unroll
  for (int m = 0; m < 8; ++m) aoffs[m] = (wm * 128 + m * 16 + lrow) * 32 + fsc;
#pragma unroll
  for (int n = 0; n < 4; ++n) boffs[n] = (wn * 64 + n * 16 + lrow) * 32 + fsc;

  f32x4 acc[8][4];
#pragma unroll
  for (int m = 0; m < 8; ++m)
#pragma unroll
    for (int n = 0; n < 4; ++n) acc[m][n] = (f32x4){0.f, 0.f, 0.f, 0.f};

  // prologue: tile 0 into buf 0, order Ak0,Bk0,Ak1,Bk1 (oldest-first)
  STG_A(0, 0, 0); STG_B(0, 0, 0); STG_A(0, 1, 0); STG_B(0, 1, 0);

  const int NK = Kd >> 6;
  for (int kt = 0; kt < NK; ++kt) {
    const int R = kt & 1, S = R ^ 1;
    const int kn = (kt + 1) * 64;
    const bool notlast = (kt + 1 < NK);
    // ---- P0 ----
    if (notlast) { STG_A(S, 0, kn); VMCNT(6); } else { VMCNT(4); }
    BAR();
    s16x8 b0[4], a0[4];
#pragma unroll
    for (int n = 0; n < 4; ++n) b0[n] = *(const s16x8*)(BSP(R, 0) + boffs[n]);
#pragma unroll
    for (int m = 0; m < 4; ++m) a0[m] = *(const s16x8*)(ASP(R, 0) + aoffs[m]);
    __builtin_amdgcn_s_setprio(1);
#pragma unroll
    for (int m = 0; m < 4; ++m)
#pragma unroll
      for (int n = 0; n < 4; ++n)
        acc[m][n] = __builtin_amdgcn_mfma_f32_16x16x32_bf16(a0[m], b0[n], acc[m][n], 0, 0, 0);
    __builtin_amdgcn_s_setprio(0);
    // ---- P1 ----
    if (notlast) STG_B(S, 0, kn);
    s16x8 a1[4];
#pragma unroll
    for (int m = 0; m < 4; ++m) a1[m] = *(const s16x8*)(ASP(R, 0) + aoffs[4 + m]);
    __builtin_amdgcn_s_setprio(1);
#pragma unroll
    for (int m = 0; m < 4; ++m)
#pragma unroll
      for (int n = 0; n < 4; ++n)
        acc[4 + m][n] = __builtin_amdgcn_mfma_f32_16x16x32_bf16(a1[m], b0[n], acc[4 + m][n], 0, 0, 0);
    __builtin_amdgcn_s_setprio(0);
    // ---- P2 ----
    if (notlast) { STG_A(S, 1, kn); VMCNT(6); } else { VMCNT(0); }
    BAR();
    s16x8 b1[4], a2[4];
#pragma unroll
    for (int n = 0; n < 4; ++n) b1[n] = *(const s16x8*)(BSP(R, 1) + boffs[n]);
#pragma unroll
    for (int m = 0; m < 4; ++m) a2[m] = *(const s16x8*)(ASP(R, 1) + aoffs[m]);
    __builtin_amdgcn_s_setprio(1);
#pragma unroll
    for (int m = 0; m < 4; ++m)
#pragma unroll
      for (int n = 0; n < 4; ++n)
        acc[m][n] = __builtin_amdgcn_mfma_f32_16x16x32_bf16(a2[m], b1[n], acc[m][n], 0, 0, 0);
    __builtin_amdgcn_s_setprio(0);
    // ---- P3 ----
    if (notlast) STG_B(S, 1, kn);
    s16x8 a3[4];
#pragma unroll
    for (int m = 0; m < 4; ++m) a3[m] = *(const s16x8*)(ASP(R, 1) + aoffs[4 + m]);
    __builtin_amdgcn_s_setprio(1);
#pragma unroll
    for (int m = 0; m < 4; ++m)
#pragma unroll
      for (int n = 0; n < 4; ++n)
        acc[4 + m][n] = __builtin_amdgcn_mfma_f32_16x16x32_bf16(a3[m], b1[n], acc[4 + m][n], 0, 0, 0);
    __builtin_amdgcn_s_setprio(0);
  }

  // epilogue
#pragma unroll
  for (int n = 0; n < 4; ++n) {
    const long c = brow0 + wn * 64 + n * 16 + lrow;
    const float bv = bias[c];
#pragma unroll
    for (int m = 0; m < 8; ++m) {
      const long r0 = arow0 + wm * 128 + m * 16 + kg * 4;
#pragma unroll
      for (int j = 0; j < 4; ++j) {
        const float val = acc[m][n][j] + bv;
        if (OUT_BF16)
          ((u16*)Cv)[(r0 + j) * N + c] = f2bf(val);
        else
          ((float*)Cv)[(r0 + j) * N + c] = val;
      }
    }
  }
#undef ASP
#undef BSP
#undef STG_A
#undef STG_B
}

// ---------------- Flash attention (causal, GQA), R4 ------------------------
// Pair-scheduled q-tiles; K double-buffered (stage kt+1 during compute of kt,
// counted vmcnt so staging spans barriers); V reg-prefetch; defer-max online
// softmax in exp2 domain; swizzled Vt/Pl.
__global__ __launch_bounds__(256, 2) void attn_kernel(
    const u16* __restrict__ Q, const u16* __restrict__ KV, u16* __restrict__ O) {
  const int p = blockIdx.x;
  const int bh = blockIdx.y;
  const int b = bh >> 5, h = bh & 31, g = h >> 2;
  const int tid = threadIdx.x, w = tid >> 6, lane = tid & 63;
  const int lrow = lane & 15, kg = lane >> 4;

  __shared__ alignas(16) u16 Ks[2][64 * 128];  // double-buffered swizzled K (32 KB)
  __shared__ alignas(16) u16 Vt[128 * 64];     // swizzled V^T (16 KB)
  __shared__ alignas(16) u16 Pl[4][16 * 64];   // per-wave P (8 KB)

  const u16* Kb = KV + (size_t)b * Tc * KVS + g * 128;
  const u16* Vb = Kb + GHDc;

  const int kv0 = (tid & 31) * 2;
  const int hc0 = (tid >> 5) * 2;

  // stage K(kt) into Ks[buf]: 4 gld_lds per thread (wave-uniform dest seg)
#define STAGEK(kt_, buf_) do { \
    const u16* Kt_ = Kb + (size_t)(kt_) * 64 * KVS; \
    _Pragma("unroll") \
    for (int i_ = 0; i_ < 4; ++i_) { \
      const int seg_ = w * 4 + i_; \
      const int kv_ = seg_ * 4 + (lane >> 4); \
      const int lc_ = (lane & 15) ^ (kv_ & 7); \
      gld_lds16(Kt_ + (size_t)kv_ * KVS + lc_ * 8, (char*)&Ks[buf_][0] + seg_ * 1024); \
    } } while (0)

  const float sc2 = 0.12751744900594938f;  // log2(e)/sqrt(128)

#pragma unroll 1
  for (int ph = 0; ph < 2; ++ph) {
    const int qt = ph ? (NT - 1 - p) : p;

    const u16* Qb = Q + ((size_t)b * Tc + (size_t)qt * 64 + w * 16 + lrow) * Dc + h * 128;
    s16x8 qf[4];
#pragma unroll
    for (int ks = 0; ks < 4; ++ks) qf[ks] = *(const s16x8*)(Qb + ks * 32 + kg * 8);

    f32x4 o[8];
#pragma unroll
    for (int n = 0; n < 8; ++n) o[n] = (f32x4){0.f, 0.f, 0.f, 0.f};
    float mrow[4], lsum[4];
#pragma unroll
    for (int j = 0; j < 4; ++j) { mrow[j] = -1e30f; lsum[j] = 0.f; }

    STAGEK(0, 0);   // prologue stage (4 loads)

#pragma unroll 1
    for (int kt = 0; kt <= qt; ++kt) {
      const int R = kt & 1;
      // --- prefetch V(kt) to regs (issued first: drained before K(kt+1)) ---
      const u16* Vtile = Vb + (size_t)kt * 64 * KVS;
      s16x8 vr[4];
#pragma unroll
      for (int i = 0; i < 4; ++i) {
        const int kv = kv0 + (i & 1), hc = hc0 + (i >> 1);
        vr[i] = *(const s16x8*)(Vtile + (size_t)kv * KVS + hc * 8);
      }
      MEMFENCE;
      // --- stage K(kt+1) into other buffer; drain K(kt) only ---
      if (kt < qt) { STAGEK(kt + 1, R ^ 1); VMCNT(8); }
      else         { VMCNT(4); }
      BAR();                                   // #A: Ks[R] visible

      // --- S = Q K^T from swizzled Ks[R] ---
      f32x4 s[4];
#pragma unroll
      for (int n = 0; n < 4; ++n) s[n] = (f32x4){0.f, 0.f, 0.f, 0.f};
#pragma unroll
      for (int n = 0; n < 4; ++n) {
        const int r = n * 16 + lrow;
#pragma unroll
        for (int ks = 0; ks < 4; ++ks) {
          const int pch = (ks * 4 + kg) ^ (lrow & 7);
          s16x8 kf = *(const s16x8*)(&Ks[R][0] + r * 128 + pch * 8);
          s[n] = __builtin_amdgcn_mfma_f32_16x16x32_bf16(qf[ks], kf, s[n], 0, 0, 0);
        }
      }

      // --- scale (exp2 domain) + causal mask on diagonal tile ---
      const int qpos = qt * 64 + w * 16 + kg * 4;
      if (kt == qt) {
#pragma unroll
        for (int n = 0; n < 4; ++n) {
          const int kvpos = kt * 64 + n * 16 + lrow;
#pragma unroll
          for (int j = 0; j < 4; ++j)
            s[n][j] = (kvpos > qpos + j) ? -1e30f : s[n][j] * sc2;
        }
      } else {
#pragma unroll
        for (int n = 0; n < 4; ++n)
#pragma unroll
          for (int j = 0; j < 4; ++j) s[n][j] *= sc2;
      }

      // --- online softmax with defer-max (THR=8 in log2 units) ---
      float rm[4];
      bool need = false;
#pragma unroll
      for (int j = 0; j < 4; ++j) {
        float m0 = fmaxf(fmaxf(s[0][j], s[1][j]), fmaxf(s[2][j], s[3][j]));
        m0 = fmaxf(m0, __shfl_xor(m0, 1));
        m0 = fmaxf(m0, __shfl_xor(m0, 2));
        m0 = fmaxf(m0, __shfl_xor(m0, 4));
        m0 = fmaxf(m0, __shfl_xor(m0, 8));
        rm[j] = m0;
        need |= (m0 > mrow[j] + 8.f);
      }
      if (__any(need)) {                        // wave-uniform rescale
#pragma unroll
        for (int j = 0; j < 4; ++j) {
          const float mnew = fmaxf(mrow[j], rm[j]);
          const float scl = exp2f(mrow[j] - mnew);
          lsum[j] *= scl;
#pragma unroll
          for (int n = 0; n < 8; ++n) o[n][j] *= scl;
          mrow[j] = mnew;
        }
      }
#pragma unroll
      for (int j = 0; j < 4; ++j) {
        float rs = 0.f;
#pragma unroll
        for (int n = 0; n < 4; ++n) {
          float pv = exp2f(s[n][j] - mrow[j]);
          s[n][j] = pv;
          rs += pv;
        }
        rs += __shfl_xor(rs, 1);
        rs += __shfl_xor(rs, 2);
        rs += __shfl_xor(rs, 4);
        rs += __shfl_xor(rs, 8);
        lsum[j] += rs;
      }

      // --- V regs ready (K(kt+1) stays in flight) ---
      if (kt < qt) { VMCNT(4); } else { VMCNT(0); }
      // --- write V^T (paired b32, swizzled) ---
#pragma unroll
      for (int a = 0; a < 2; ++a) {
        const int hd0 = (hc0 + a) * 8;
#pragma unroll
        for (int e = 0; e < 8; ++e) {
          const int hd = hd0 + e;
          const u32 pk = (u32)(u16)vr[a * 2 + 0][e] | ((u32)(u16)vr[a * 2 + 1][e] << 16);
          *(u32*)(Vt + hd * 64 + (((kv0 >> 3) ^ (hd & 7)) * 8) + (kv0 & 7)) = pk;
        }
      }
      // --- write P (swizzled) ---
      u16* Pw = Pl[w];
#pragma unroll
      for (int n = 0; n < 4; ++n)
#pragma unroll
        for (int j = 0; j < 4; ++j) {
          const int q = kg * 4 + j;
          const int kv = n * 16 + lrow;
          Pw[q * 64 + (((kv >> 3) ^ (q & 7)) * 8) + (kv & 7)] = f2bf(s[n][j]);
        }
      LGKM0();
      BAR();                                   // #B: Vt/Pl visible

      // --- O += P V ---
#pragma unroll
      for (int ks2 = 0; ks2 < 2; ++ks2) {
        const int pch = (ks2 * 4 + kg) ^ (lrow & 7);
        s16x8 pa = *(const s16x8*)(Pw + lrow * 64 + pch * 8);
#pragma unroll
        for (int n = 0; n < 8; ++n) {
          const int hd = n * 16 + lrow;
          s16x8 vb = *(const s16x8*)(Vt + hd * 64 + pch * 8);
          o[n] = __builtin_amdgcn_mfma_f32_16x16x32_bf16(pa, vb, o[n], 0, 0, 0);
        }
      }
      BAR();                                   // #C: Vt/Pl reads done
    }

    // --- normalize + write ---
    u16* Ob = O + ((size_t)b * Tc + (size_t)qt * 64 + w * 16) * Dc + h * 128;
#pragma unroll
    for (int j = 0; j < 4; ++j) {
      const float inv = 1.f / lsum[j];
      const int r = kg * 4 + j;
#pragma unroll
      for (int n = 0; n < 8; ++n)
        Ob[(size_t)r * Dc + n * 16 + lrow] = f2bf(o[n][j] * inv);
    }
  }
#undef STAGEK
}

// ---------------------------------------------------------------------------
extern "C" void kernel_launch(void* const* d_in, const int* in_sizes, int n_in,
                              void* d_out, int out_size, void* d_ws, size_t ws_size,
                              hipStream_t stream) {
  (void)in_sizes; (void)n_in; (void)out_size; (void)ws_size;
  const float* x  = (const float*)d_in[0];
  const float* Wq = (const float*)d_in[2];
  const float* bq = (const float*)d_in[3];
  const float* Wk = (const float*)d_in[4];
  const float* bk = (const float*)d_in[5];
  const float* Wv = (const float*)d_in[6];
  const float* bv = (const float*)d_in[7];
  const float* Wo = (const float*)d_in[8];
  const float* bo = (const float*)d_in[9];
  float* out = (float*)d_out;

  char* ws = (char*)d_ws;
  u16* xb   = (u16*)(ws);                    // 32M, reused as AOb
  u16* Qb   = (u16*)(ws + 33554432);         // 32M
  u16* Wqt  = (u16*)(ws + 67108864);         // 32M, reused as KVb (16M)
  u16* WKVt = (u16*)(ws + 100663296);        // 16M
  u16* Wot  = (u16*)(ws + 117440512);        // 32M
  float* bkv = (float*)(ws + 150994944);     // 8K
  u16* KVb  = (u16*)(ws + 67108864);
  u16* AOb  = xb;

  const int M = Bc * Tc;  // 4096

  cast_bf16<<<(M * Dc / 4 + 255) / 256, 256, 0, stream>>>(x, xb, M * Dc / 4);
  castT<<<dim3(Dc / 32, Dc / 32), 256, 0, stream>>>(Wq, Wqt, Dc, Dc);
  castT<<<dim3(GHDc / 32, Dc / 32), 256, 0, stream>>>(Wk, WKVt, Dc, GHDc);
  castT<<<dim3(GHDc / 32, Dc / 32), 256, 0, stream>>>(Wv, WKVt + (size_t)GHDc * Dc, Dc, GHDc);
  castT<<<dim3(Dc / 32, Dc / 32), 256, 0, stream>>>(Wo, Wot, Dc, Dc);
  concat_bias<<<8, 256, 0, stream>>>(bk, bv, bkv);

  // Q-proj: 256² pipelined GEMM (dynamic LDS 128KB)
  gemm256<1><<<dim3(Dc / 256, M / 256), 512, 131072, stream>>>(xb, Wqt, bq, Qb, Dc, Dc);
  // KV-proj: m97 128²
  gemm_bt<1><<<dim3(KVS / 128, M / 128), 256, 0, stream>>>(xb, WKVt, bkv, KVb, KVS, Dc);

  attn_kernel<<<dim3(NT / 2, Bc * Hc), 256, 0, stream>>>(Qb, KVb, AOb);

  // O-proj: 256² pipelined GEMM, fp32 out
  gemm256<0><<<dim3(Dc / 256, M / 256), 512, 131072, stream>>>(AOb, Wot, bo, out, Dc, Dc);
}